// Round 11
// baseline (351.032 us; speedup 1.0000x reference)
//
#include <hip/hip_runtime.h>
#include <hip/hip_bf16.h>
#include <math.h>

#define N_NODES 50000
#define N_EDGES 800000
#define N_GRAPHS 64
#define HID 128
#define N_CLASSES 10
#define N_LAYERS 3
#define NEG_SLOPE 0.2f

#define NB 196        // dst buckets of 256 nodes
#define BCAP 5120     // slots per bucket (mean ~4337, sigma ~66 -> +12 sigma)
#define ACHUNK 4096   // edges per partition block

typedef __attribute__((ext_vector_type(8))) short short8;
typedef __attribute__((ext_vector_type(4))) float f32x4;
typedef __attribute__((ext_vector_type(2))) _Float16 h2;

extern "C" __device__ _Float16 __ocml_exp2_f16(_Float16);

__device__ inline ushort f2bf(float f) {
    uint u = __builtin_bit_cast(uint, f);
    u += 0x7fffu + ((u >> 16) & 1u);      // RNE
    return (ushort)(u >> 16);
}
__device__ inline uint pk2bf(float a, float b) {
    return (uint)f2bf(a) | ((uint)f2bf(b) << 16);
}
__device__ inline h2 pkh(float a, float b) {
    return __builtin_bit_cast(h2, __builtin_amdgcn_cvt_pkrtz(a, b));
}

// ---------------- setup: x/W bf16 prep + edge partition, one launch ----------------

__global__ __launch_bounds__(256) void setup_kernel(
    const float* __restrict__ x, uint* __restrict__ xb, int n,
    const float* __restrict__ Wl, const float* __restrict__ Wr,
    uint* __restrict__ wt, int wtot,
    const int* __restrict__ ei, int E,
    int* __restrict__ bptr, uint* __restrict__ bbuf,
    int xqb, int wb) {
    __shared__ int hcnt[256];
    __shared__ int hexcl[256];
    __shared__ int lofs[256];
    __shared__ int delta[256];
    __shared__ uint stage[ACHUNK];
    int t = threadIdx.x;
    int blk = blockIdx.x;

    if (blk < xqb) {                      // ---- x prep: 1 uint4 (8 floats) per thread
        int j = blk * 256 + t;
        if (j < n * 16) {
            const float4* xp = (const float4*)x + (size_t)j * 2;
            float4 a = xp[0], b = xp[1];
            uint4 o;
            o.x = pk2bf(a.x, a.y); o.y = pk2bf(a.z, a.w);
            o.z = pk2bf(b.x, b.y); o.w = pk2bf(b.z, b.w);
            ((uint4*)xb)[j] = o;
        }
        return;
    }
    blk -= xqb;
    if (blk < wb) {                       // ---- W prep (bf16)
        int i = blk * 256 + t;
        if (i >= wtot) return;
        int kp = i & 63;
        int nn = (i >> 6) & 255;
        int l  = i >> 14;
        const float* W = (nn < 128) ? Wl : Wr;
        int c = nn & 127;
        wt[i] = pk2bf(W[l * 16384 + (2 * kp) * 128 + c],
                      W[l * 16384 + (2 * kp + 1) * 128 + c]);
        return;
    }
    blk -= wb;                            // ---- partition
    int total = E + n;
    int base = blk * ACHUNK;
    int cntblk = min(ACHUNK, total - base);
    hcnt[t] = 0; lofs[t] = 0;
    __syncthreads();

    uint v[16]; int bk[16];
#pragma unroll
    for (int j = 0; j < 16; ++j) {
        int e = base + j * 256 + t;
        bk[j] = -1;
        if (e < total) {
            int s, d;
            if (e < E) { s = ei[e]; d = ei[E + e]; }
            else       { s = e - E; d = e - E; }
            v[j] = ((uint)s << 16) | (uint)d;    // src,dst both < 65536
            bk[j] = d >> 8;
            atomicAdd(&hcnt[bk[j]], 1);
        }
    }
    __syncthreads();
    int hv = hcnt[t];
    __shared__ int stmp[256];
    stmp[t] = hv;
    __syncthreads();
    for (int off = 1; off < 256; off <<= 1) {
        int u = (t >= off) ? stmp[t - off] : 0;
        __syncthreads();
        stmp[t] += u;
        __syncthreads();
    }
    hexcl[t] = stmp[t] - hv;
    __syncthreads();
#pragma unroll
    for (int j = 0; j < 16; ++j) {
        if (bk[j] >= 0) {
            int pos = hexcl[bk[j]] + atomicAdd(&lofs[bk[j]], 1);
            stage[pos] = v[j];
        }
    }
    __syncthreads();
    if (t < NB) {
        int c = hcnt[t];
        int gb = c ? atomicAdd(&bptr[t], c) : 0;
        delta[t] = t * BCAP + gb - hexcl[t];
    }
    __syncthreads();
    for (int idx = t; idx < cntblk; idx += 256) {
        uint val = stage[idx];
        int b = (val >> 8) & 0xff;
        int tgt = delta[b] + idx;
        if (tgt < (b + 1) * BCAP) bbuf[tgt] = val;
    }
}

// ---------------- bucket CSR (blocks 0..NB) + gemm layer 0 (rest), one launch --------
// gemm inputs A,W stay bf16; OUTPUT xl/xr is fp16 (consumed only by attn).

__device__ __forceinline__ void gemm_body(
    const ushort* __restrict__ A, const ushort* __restrict__ Wt,
    const float* __restrict__ bl, const float* __restrict__ br,
    ushort* __restrict__ xlb, ushort* __restrict__ xrb, int n, int bid, int tid) {
    int wv = tid >> 6;
    int lane = tid & 63;
    int q = lane >> 4, m16 = lane & 15;
    int m0 = bid * 64;

    short8 bf[4][4];
#pragma unroll
    for (int nt = 0; nt < 4; ++nt) {
        const ushort* wp = Wt + (size_t)(wv * 64 + nt * 16 + m16) * 128 + q * 8;
#pragma unroll
        for (int ks = 0; ks < 4; ++ks) bf[nt][ks] = *(const short8*)(wp + ks * 32);
    }
    const ushort* ap[4];
#pragma unroll
    for (int mt = 0; mt < 4; ++mt) {
        int r = m0 + mt * 16 + m16;
        if (r > n - 1) r = n - 1;
        ap[mt] = A + (size_t)r * 128 + q * 8;
    }

    f32x4 z = {0.f, 0.f, 0.f, 0.f};
    f32x4 acc[4][4];
#pragma unroll
    for (int mt = 0; mt < 4; ++mt)
#pragma unroll
        for (int nt = 0; nt < 4; ++nt) acc[mt][nt] = z;

#pragma unroll
    for (int ks = 0; ks < 4; ++ks) {
        short8 af[4];
#pragma unroll
        for (int mt = 0; mt < 4; ++mt) af[mt] = *(const short8*)(ap[mt] + ks * 32);
#pragma unroll
        for (int mt = 0; mt < 4; ++mt)
#pragma unroll
            for (int nt = 0; nt < 4; ++nt)
                acc[mt][nt] = __builtin_amdgcn_mfma_f32_16x16x32_bf16(
                    bf[nt][ks], af[mt], acc[mt][nt], 0, 0, 0);
    }

    ushort* outp = (wv >= 2) ? xrb : xlb;
    const float* bx = (wv >= 2) ? br : bl;
    int fb = (wv & 1) * 64;
#pragma unroll
    for (int nt = 0; nt < 4; ++nt) {
        int fcol = fb + nt * 16 + q * 4;
        float4 b4 = *(const float4*)&bx[fcol];
#pragma unroll
        for (int mt = 0; mt < 4; ++mt) {
            int m = m0 + mt * 16 + m16;
            if (m < n) {
                uint2 pk;
                pk.x = __builtin_bit_cast(uint, pkh(acc[mt][nt][0] + b4.x,
                                                    acc[mt][nt][1] + b4.y));
                pk.y = __builtin_bit_cast(uint, pkh(acc[mt][nt][2] + b4.z,
                                                    acc[mt][nt][3] + b4.w));
                *(uint2*)&outp[(size_t)m * 128 + fcol] = pk;
            }
        }
    }
}

__global__ __launch_bounds__(256) void csr_gemm0_kernel(
    const int* __restrict__ bptr, const uint* __restrict__ bbuf, int n,
    int* __restrict__ row_start, int* __restrict__ ssrc,
    const ushort* __restrict__ A, const ushort* __restrict__ Wt,
    const float* __restrict__ bl, const float* __restrict__ br,
    ushort* __restrict__ xlb, ushort* __restrict__ xrb) {
    int t = threadIdx.x;
    if (blockIdx.x >= NB) {
        gemm_body(A, Wt, bl, br, xlb, xrb, n, blockIdx.x - NB, t);
        return;
    }
    int b = blockIdx.x;
    __shared__ int sb[256], h[256], hx[256], lofs[256];
    int bv = (t < NB) ? min(bptr[t], BCAP) : 0;
    sb[t] = bv;
    __syncthreads();
    for (int off = 1; off < 256; off <<= 1) {
        int u = (t >= off) ? sb[t - off] : 0;
        __syncthreads();
        sb[t] += u;
        __syncthreads();
    }
    int cnt = min(bptr[b], BCAP);
    int base = sb[b] - cnt;               // exclusive prefix
    if (b == NB - 1 && t == 0) row_start[n] = sb[NB - 1];
    h[t] = 0; lofs[t] = 0;
    __syncthreads();
    const uint* bp = bbuf + (size_t)b * BCAP;
    for (int k = t; k < cnt; k += 256) atomicAdd(&h[bp[k] & 255u], 1);
    __syncthreads();
    int hv = h[t];
    hx[t] = hv;
    __syncthreads();
    for (int off = 1; off < 256; off <<= 1) {
        int u = (t >= off) ? hx[t - off] : 0;
        __syncthreads();
        hx[t] += u;
        __syncthreads();
    }
    int excl = hx[t] - hv;
    int node = (b << 8) + t;
    if (node < n) row_start[node] = base + excl;
    __syncthreads();
    h[t] = excl;
    __syncthreads();
    for (int k = t; k < cnt; k += 256) {
        uint val = bp[k];
        int dl = val & 255u;
        int pos = base + h[dl] + atomicAdd(&lofs[dl], 1);
        ssrc[pos] = (int)((val & 0xffff0000u) >> 8);   // src*256 byte offset
    }
}

__global__ __launch_bounds__(256) void gemm_mfma(
    const ushort* __restrict__ A, const ushort* __restrict__ Wt,
    const float* __restrict__ bl, const float* __restrict__ br,
    ushort* __restrict__ xlb, ushort* __restrict__ xrb, int n) {
    gemm_body(A, Wt, bl, br, xlb, xrb, n, blockIdx.x, threadIdx.x);
}

// ---------------- fused attention: packed-f16 datapath + packed shuffle reduce -------
// xl/xr fp16 pairs. Scores carry a built-in -8 shift (EINIT -0.5/lane, 8-lane head
// sum) so exp2 weights <= 0.25 and f16 den/acc cannot overflow; the 2^-8 cancels in
// the softmax division. Edge-pair scores are packed into one h2 -> 3 shfl per pair.

#define SLOTE(u, u01, u23, eh)                             \
    h2 u01 = __builtin_bit_cast(h2, u.x);                  \
    h2 u23 = __builtin_bit_cast(h2, u.y);                  \
    h2 eh;                                                 \
    {                                                      \
        h2 t01 = u01 + xr01, t23 = u23 + xr23;             \
        t01 = __builtin_elementwise_max(t01, t01 * K02);   \
        t23 = __builtin_elementwise_max(t23, t23 * K02);   \
        eh = EINIT + at01 * t01;                           \
        eh += at23 * t23;                                  \
    }

__device__ inline uint packpair(h2 a, h2 b) {   // -> (a.x+a.y, b.x+b.y)
    h2 lo = {a.x, b.x};
    h2 hi = {a.y, b.y};
    return __builtin_bit_cast(uint, lo + hi);
}
__device__ inline uint shfl_add_h2(uint q, int m) {
    uint r = (uint)__shfl_xor((int)q, m);
    h2 s = __builtin_bit_cast(h2, q) + __builtin_bit_cast(h2, r);
    return __builtin_bit_cast(uint, s);
}

__global__ __launch_bounds__(256) void attn_kernel(
    const uint* __restrict__ xlb, const uint* __restrict__ xrb,
    const float* __restrict__ att, const float* __restrict__ bias,
    const int* __restrict__ row_start, const int* __restrict__ ssrc,
    uint* __restrict__ hout, int n) {
    int wave = threadIdx.x >> 6;
    int lane = threadIdx.x & 63;
    int half = lane >> 5;
    int l32  = lane & 31;
    int i = blockIdx.x * 4 + wave;
    if (i >= n) return;

    const char* xlB = (const char*)xlb;
    int lofs = l32 * 8;

    uint2 xru = *(const uint2*)((const char*)xrb + (size_t)i * 256 + lofs);
    h2 xr01 = __builtin_bit_cast(h2, xru.x);
    h2 xr23 = __builtin_bit_cast(h2, xru.y);
    const float L2E = 1.4426950408889634f;
    float4 at = ((const float4*)att)[l32];
    h2 at01 = pkh(at.x * L2E, at.y * L2E);
    h2 at23 = pkh(at.z * L2E, at.w * L2E);
    const h2 K02   = {(_Float16)0.2f, (_Float16)0.2f};
    const h2 EINIT = {(_Float16)-0.5f, (_Float16)-0.5f};

    int p0 = row_start[i], p1 = row_start[i + 1];

    h2 denP = {0, 0};
    h2 aA01 = {0, 0}, aA23 = {0, 0};      // slots 0,2 (weighted by w01.x / w23.x)
    h2 aB01 = {0, 0}, aB23 = {0, 0};      // slots 1,3

    int p = p0;
    for (; p + 8 <= p1; p += 8) {          // 8 edges: 4 gathers in flight
        uint s0 = (uint)ssrc[p + half];
        uint s1 = (uint)ssrc[p + 2 + half];
        uint s2 = (uint)ssrc[p + 4 + half];
        uint s3 = (uint)ssrc[p + 6 + half];
        uint2 u0 = *(const uint2*)(xlB + (size_t)s0 + lofs);
        uint2 u1 = *(const uint2*)(xlB + (size_t)s1 + lofs);
        uint2 u2 = *(const uint2*)(xlB + (size_t)s2 + lofs);
        uint2 u3 = *(const uint2*)(xlB + (size_t)s3 + lofs);
        SLOTE(u0, v001, v023, eh0);
        SLOTE(u1, v101, v123, eh1);
        SLOTE(u2, v201, v223, eh2);
        SLOTE(u3, v301, v323, eh3);
        uint q01 = packpair(eh0, eh1);
        uint q23 = packpair(eh2, eh3);
        q01 = shfl_add_h2(q01, 1); q23 = shfl_add_h2(q23, 1);
        q01 = shfl_add_h2(q01, 2); q23 = shfl_add_h2(q23, 2);
        q01 = shfl_add_h2(q01, 4); q23 = shfl_add_h2(q23, 4);
        h2 e01 = __builtin_bit_cast(h2, q01);
        h2 e23 = __builtin_bit_cast(h2, q23);
        h2 w01, w23;
        w01.x = __ocml_exp2_f16(e01.x); w01.y = __ocml_exp2_f16(e01.y);
        w23.x = __ocml_exp2_f16(e23.x); w23.y = __ocml_exp2_f16(e23.y);
        denP += w01; denP += w23;
        h2 wA = {w01.x, w01.x}, wB = {w01.y, w01.y};
        h2 wC = {w23.x, w23.x}, wD = {w23.y, w23.y};
        aA01 += wA * v001; aA23 += wA * v023;
        aB01 += wB * v101; aB23 += wB * v123;
        aA01 += wC * v201; aA23 += wC * v223;
        aB01 += wD * v301; aB23 += wD * v323;
    }
    if (p < p1) {                           // masked epilogue: 1..7 edges
        int lst = p1 - 1;
        int i0 = p + half, i1 = p + 2 + half, i2 = p + 4 + half, i3 = p + 6 + half;
        uint s0 = (uint)ssrc[min(i0, lst)];
        uint s1 = (uint)ssrc[min(i1, lst)];
        uint s2 = (uint)ssrc[min(i2, lst)];
        uint s3 = (uint)ssrc[min(i3, lst)];
        uint2 u0 = *(const uint2*)(xlB + (size_t)s0 + lofs);
        uint2 u1 = *(const uint2*)(xlB + (size_t)s1 + lofs);
        uint2 u2 = *(const uint2*)(xlB + (size_t)s2 + lofs);
        uint2 u3 = *(const uint2*)(xlB + (size_t)s3 + lofs);
        SLOTE(u0, v001, v023, eh0);
        SLOTE(u1, v101, v123, eh1);
        SLOTE(u2, v201, v223, eh2);
        SLOTE(u3, v301, v323, eh3);
        uint q01 = packpair(eh0, eh1);
        uint q23 = packpair(eh2, eh3);
        q01 = shfl_add_h2(q01, 1); q23 = shfl_add_h2(q23, 1);
        q01 = shfl_add_h2(q01, 2); q23 = shfl_add_h2(q23, 2);
        q01 = shfl_add_h2(q01, 4); q23 = shfl_add_h2(q23, 4);
        h2 e01 = __builtin_bit_cast(h2, q01);
        h2 e23 = __builtin_bit_cast(h2, q23);
        h2 w01, w23;
        const _Float16 zh = (_Float16)0.f;
        w01.x = (i0 < p1) ? __ocml_exp2_f16(e01.x) : zh;
        w01.y = (i1 < p1) ? __ocml_exp2_f16(e01.y) : zh;
        w23.x = (i2 < p1) ? __ocml_exp2_f16(e23.x) : zh;
        w23.y = (i3 < p1) ? __ocml_exp2_f16(e23.y) : zh;
        denP += w01; denP += w23;
        h2 wA = {w01.x, w01.x}, wB = {w01.y, w01.y};
        h2 wC = {w23.x, w23.x}, wD = {w23.y, w23.y};
        aA01 += wA * v001; aA23 += wA * v023;
        aB01 += wB * v101; aB23 += wB * v123;
        aA01 += wC * v201; aA23 += wC * v223;
        aB01 += wD * v301; aB23 += wD * v323;
    }

    float den = (float)denP.x + (float)denP.y;
    float a0 = (float)(_Float16)(aA01.x + aB01.x);
    float a1 = (float)(_Float16)(aA01.y + aB01.y);
    float a2 = (float)(_Float16)(aA23.x + aB23.x);
    float a3 = (float)(_Float16)(aA23.y + aB23.y);
    den += __shfl_xor(den, 32);
    a0 += __shfl_xor(a0, 32);
    a1 += __shfl_xor(a1, 32);
    a2 += __shfl_xor(a2, 32);
    a3 += __shfl_xor(a3, 32);

    if (half == 0) {
        float inv = 1.f / den;
        float4 bi = ((const float4*)bias)[l32];
        float o0 = a0 * inv + bi.x; o0 = o0 > 0.f ? o0 : __expf(o0) - 1.f;
        float o1 = a1 * inv + bi.y; o1 = o1 > 0.f ? o1 : __expf(o1) - 1.f;
        float o2 = a2 * inv + bi.z; o2 = o2 > 0.f ? o2 : __expf(o2) - 1.f;
        float o3 = a3 * inv + bi.w; o3 = o3 > 0.f ? o3 : __expf(o3) - 1.f;
        uint2 pk;
        pk.x = pk2bf(o0, o1);
        pk.y = pk2bf(o2, o3);
        *(uint2*)((char*)hout + (size_t)i * 256 + lofs) = pk;
    }
}

// ---------------- pooling: atomic-free partials psum[y][g][128] ----------------

__device__ inline float bflo(uint v) { return __builtin_bit_cast(float, v << 16); }
__device__ inline float bfhi(uint v) { return __builtin_bit_cast(float, v & 0xffff0000u); }

__global__ __launch_bounds__(256) void pool_kernel(const uint* __restrict__ h2v,
                                                   const int* __restrict__ batch, int n,
                                                   float* __restrict__ psum) {
    int g = blockIdx.x;
    int t = threadIdx.x;
    int cp = t & 63;
    int sub = (t >> 6) | (blockIdx.y << 2);   // 0..31
    int b, e;
    {
        int lo = 0, hi = n;
        while (lo < hi) { int mid = (lo + hi) >> 1; if (batch[mid] < g) lo = mid + 1; else hi = mid; }
        b = lo;
        lo = 0; hi = n;
        int g1 = g + 1;
        while (lo < hi) { int mid = (lo + hi) >> 1; if (batch[mid] < g1) lo = mid + 1; else hi = mid; }
        e = lo;
    }
    float a0 = 0.f, a1 = 0.f;
    for (int i = b + sub; i < e; i += 32) {
        uint u = h2v[(size_t)i * 64 + cp];
        a0 += bflo(u); a1 += bfhi(u);
    }
    __shared__ float r0[256], r1[256];
    r0[t] = a0; r1[t] = a1;
    __syncthreads();
    if (t < 64) {
        float s0 = r0[t] + r0[t + 64] + r0[t + 128] + r0[t + 192];
        float s1 = r1[t] + r1[t + 64] + r1[t + 128] + r1[t + 192];
        float* pp = &psum[((size_t)blockIdx.y * 64 + g) * 128];
        pp[2 * t]     = s0;
        pp[2 * t + 1] = s1;
    }
}

__global__ void final_kernel(const float* __restrict__ psum, const int* __restrict__ batch,
                             int n, const float* __restrict__ lw,
                             const float* __restrict__ lb, float* __restrict__ out) {
    int g = threadIdx.x;
    if (g >= N_GRAPHS) return;
    int b, e;
    {
        int lo = 0, hi = n;
        while (lo < hi) { int mid = (lo + hi) >> 1; if (batch[mid] < g) lo = mid + 1; else hi = mid; }
        b = lo;
        lo = 0; hi = n;
        int g1 = g + 1;
        while (lo < hi) { int mid = (lo + hi) >> 1; if (batch[mid] < g1) lo = mid + 1; else hi = mid; }
        e = lo;
    }
    float invc = 1.f / fmaxf((float)(e - b), 1.f);
    float z[N_CLASSES];
#pragma unroll
    for (int c = 0; c < N_CLASSES; ++c) z[c] = lb[c];
    for (int k = 0; k < 128; ++k) {
        float p = 0.f;
#pragma unroll
        for (int y = 0; y < 8; ++y) p += psum[((size_t)y * 64 + g) * 128 + k];
        p *= invc;
#pragma unroll
        for (int c = 0; c < N_CLASSES; ++c) z[c] += p * lw[k * N_CLASSES + c];
    }
    float mx = -1e30f;
#pragma unroll
    for (int c = 0; c < N_CLASSES; ++c) {
        z[c] = z[c] > 0.f ? z[c] : expf(z[c]) - 1.f;
        mx = fmaxf(mx, z[c]);
    }
    float s = 0.f;
#pragma unroll
    for (int c = 0; c < N_CLASSES; ++c) s += expf(z[c] - mx);
    float lse = mx + logf(s);
#pragma unroll
    for (int c = 0; c < N_CLASSES; ++c) out[g * N_CLASSES + c] = z[c] - lse;
}

// ---------------- launch ----------------

extern "C" void kernel_launch(void* const* d_in, const int* in_sizes, int n_in,
                              void* d_out, int out_size, void* d_ws, size_t ws_size,
                              hipStream_t stream) {
    const float* x     = (const float*)d_in[0];
    const int*   ei    = (const int*)d_in[1];
    const int*   batch = (const int*)d_in[2];
    const float* Wl    = (const float*)d_in[3];
    const float* Wr    = (const float*)d_in[4];
    const float* bl    = (const float*)d_in[5];
    const float* br    = (const float*)d_in[6];
    const float* att   = (const float*)d_in[7];
    const float* bias  = (const float*)d_in[8];
    const float* lw    = (const float*)d_in[9];
    const float* lb    = (const float*)d_in[10];
    float* out = (float*)d_out;

    const int n = in_sizes[2];         // 50000
    const int E = in_sizes[1] / 2;     // 800000
    const int total_edges = E + n;

    char* ws = (char*)d_ws;
    size_t o = 0;
    auto alloc = [&](size_t bytes) -> void* {
        void* p = ws + o;
        o = (o + bytes + 255) & ~(size_t)255;
        return p;
    };
    int*    row_start = (int*)alloc((size_t)(n + 1) * 4);
    int*    bptr      = (int*)alloc((size_t)NB * 4);
    uint*   bbuf      = (uint*)alloc((size_t)NB * BCAP * 4);
    int*    ssrc      = (int*)alloc((size_t)total_edges * 4);
    ushort* xbf0      = (ushort*)alloc((size_t)n * HID * 2);
    ushort* xlb       = (ushort*)alloc((size_t)n * HID * 2);
    ushort* xrb       = (ushort*)alloc((size_t)n * HID * 2);
    ushort* hbA       = (ushort*)alloc((size_t)n * HID * 2);
    ushort* hbB       = (ushort*)alloc((size_t)n * HID * 2);
    uint*   wt        = (uint*)alloc((size_t)N_LAYERS * 256 * 64 * 4);
    float*  psum      = (float*)alloc((size_t)8 * N_GRAPHS * HID * 4);

    hipMemsetAsync(bptr, 0, (size_t)NB * 4, stream);

    int wtot = N_LAYERS * 256 * 64;
    int xqb = (n * 16 + 255) / 256;                       // 3125
    int wb  = (wtot + 255) / 256;                         // 192
    int pb  = (total_edges + ACHUNK - 1) / ACHUNK;        // 208
    setup_kernel<<<xqb + wb + pb, 256, 0, stream>>>(
        x, (uint*)xbf0, n, Wl, Wr, wt, wtot, ei, E, bptr, bbuf, xqb, wb);

    int mblocks = (n + 63) / 64;
    int ablocks = (n + 3) / 4;

    csr_gemm0_kernel<<<NB + mblocks, 256, 0, stream>>>(
        bptr, bbuf, n, row_start, ssrc,
        xbf0, (const ushort*)wt, bl, br, xlb, xrb);

    attn_kernel<<<ablocks, 256, 0, stream>>>((const uint*)xlb, (const uint*)xrb,
                                             att, bias, row_start, ssrc, (uint*)hbA, n);
    gemm_mfma<<<mblocks, 256, 0, stream>>>(hbA, (const ushort*)(wt + (size_t)256 * 64),
                                           bl + HID, br + HID, xlb, xrb, n);
    attn_kernel<<<ablocks, 256, 0, stream>>>((const uint*)xlb, (const uint*)xrb,
                                             att + HID, bias + HID, row_start, ssrc,
                                             (uint*)hbB, n);
    gemm_mfma<<<mblocks, 256, 0, stream>>>(hbB, (const ushort*)(wt + (size_t)2 * 256 * 64),
                                           bl + 2 * HID, br + 2 * HID, xlb, xrb, n);
    attn_kernel<<<ablocks, 256, 0, stream>>>((const uint*)xlb, (const uint*)xrb,
                                             att + 2 * HID, bias + 2 * HID, row_start, ssrc,
                                             (uint*)hbA, n);

    pool_kernel<<<dim3(N_GRAPHS, 8), 256, 0, stream>>>((const uint*)hbA, batch, n, psum);
    final_kernel<<<1, 64, 0, stream>>>(psum, batch, n, lw, lb, out);
}

// Round 12
// 336.524 us; speedup vs baseline: 1.0431x; 1.0431x over previous
//
#include <hip/hip_runtime.h>
#include <hip/hip_bf16.h>
#include <math.h>

#define N_NODES 50000
#define N_EDGES 800000
#define N_GRAPHS 64
#define HID 128
#define N_CLASSES 10
#define N_LAYERS 3
#define NEG_SLOPE 0.2f

#define NB 196        // dst buckets of 256 nodes
#define BCAP 5120     // slots per bucket (mean ~4337, sigma ~66 -> +12 sigma)
#define ACHUNK 4096   // edges per partition block

typedef __attribute__((ext_vector_type(8))) short short8;
typedef __attribute__((ext_vector_type(4))) float f32x4;
typedef __attribute__((ext_vector_type(2))) _Float16 h2;

extern "C" __device__ _Float16 __ocml_exp2_f16(_Float16);

__device__ inline ushort f2bf(float f) {
    uint u = __builtin_bit_cast(uint, f);
    u += 0x7fffu + ((u >> 16) & 1u);      // RNE
    return (ushort)(u >> 16);
}
__device__ inline uint pk2bf(float a, float b) {
    return (uint)f2bf(a) | ((uint)f2bf(b) << 16);
}
__device__ inline h2 pkh(float a, float b) {
    return __builtin_bit_cast(h2, __builtin_amdgcn_cvt_pkrtz(a, b));
}

// ---------------- setup: x/W bf16 prep + edge partition, one launch ----------------

__global__ __launch_bounds__(256) void setup_kernel(
    const float* __restrict__ x, uint* __restrict__ xb, int n,
    const float* __restrict__ Wl, const float* __restrict__ Wr,
    uint* __restrict__ wt, int wtot,
    const int* __restrict__ ei, int E,
    int* __restrict__ bptr, uint* __restrict__ bbuf,
    int xqb, int wb) {
    __shared__ int hcnt[256];
    __shared__ int hexcl[256];
    __shared__ int lofs[256];
    __shared__ int delta[256];
    __shared__ uint stage[ACHUNK];
    int t = threadIdx.x;
    int blk = blockIdx.x;

    if (blk < xqb) {                      // ---- x prep: 1 uint4 (8 floats) per thread
        int j = blk * 256 + t;
        if (j < n * 16) {
            const float4* xp = (const float4*)x + (size_t)j * 2;
            float4 a = xp[0], b = xp[1];
            uint4 o;
            o.x = pk2bf(a.x, a.y); o.y = pk2bf(a.z, a.w);
            o.z = pk2bf(b.x, b.y); o.w = pk2bf(b.z, b.w);
            ((uint4*)xb)[j] = o;
        }
        return;
    }
    blk -= xqb;
    if (blk < wb) {                       // ---- W prep (bf16)
        int i = blk * 256 + t;
        if (i >= wtot) return;
        int kp = i & 63;
        int nn = (i >> 6) & 255;
        int l  = i >> 14;
        const float* W = (nn < 128) ? Wl : Wr;
        int c = nn & 127;
        wt[i] = pk2bf(W[l * 16384 + (2 * kp) * 128 + c],
                      W[l * 16384 + (2 * kp + 1) * 128 + c]);
        return;
    }
    blk -= wb;                            // ---- partition
    int total = E + n;
    int base = blk * ACHUNK;
    int cntblk = min(ACHUNK, total - base);
    hcnt[t] = 0; lofs[t] = 0;
    __syncthreads();

    uint v[16]; int bk[16];
#pragma unroll
    for (int j = 0; j < 16; ++j) {
        int e = base + j * 256 + t;
        bk[j] = -1;
        if (e < total) {
            int s, d;
            if (e < E) { s = ei[e]; d = ei[E + e]; }
            else       { s = e - E; d = e - E; }
            v[j] = ((uint)s << 16) | (uint)d;    // src,dst both < 65536
            bk[j] = d >> 8;
            atomicAdd(&hcnt[bk[j]], 1);
        }
    }
    __syncthreads();
    int hv = hcnt[t];
    __shared__ int stmp[256];
    stmp[t] = hv;
    __syncthreads();
    for (int off = 1; off < 256; off <<= 1) {
        int u = (t >= off) ? stmp[t - off] : 0;
        __syncthreads();
        stmp[t] += u;
        __syncthreads();
    }
    hexcl[t] = stmp[t] - hv;
    __syncthreads();
#pragma unroll
    for (int j = 0; j < 16; ++j) {
        if (bk[j] >= 0) {
            int pos = hexcl[bk[j]] + atomicAdd(&lofs[bk[j]], 1);
            stage[pos] = v[j];
        }
    }
    __syncthreads();
    if (t < NB) {
        int c = hcnt[t];
        int gb = c ? atomicAdd(&bptr[t], c) : 0;
        delta[t] = t * BCAP + gb - hexcl[t];
    }
    __syncthreads();
    for (int idx = t; idx < cntblk; idx += 256) {
        uint val = stage[idx];
        int b = (val >> 8) & 0xff;
        int tgt = delta[b] + idx;
        if (tgt < (b + 1) * BCAP) bbuf[tgt] = val;
    }
}

// ---------------- bucket CSR (blocks 0..NB) + gemm layer 0 (rest), one launch --------
// gemm inputs A,W stay bf16; OUTPUT xl/xr is fp16 (consumed only by attn).

__device__ __forceinline__ void gemm_body(
    const ushort* __restrict__ A, const ushort* __restrict__ Wt,
    const float* __restrict__ bl, const float* __restrict__ br,
    ushort* __restrict__ xlb, ushort* __restrict__ xrb, int n, int bid, int tid) {
    int wv = tid >> 6;
    int lane = tid & 63;
    int q = lane >> 4, m16 = lane & 15;
    int m0 = bid * 64;

    short8 bf[4][4];
#pragma unroll
    for (int nt = 0; nt < 4; ++nt) {
        const ushort* wp = Wt + (size_t)(wv * 64 + nt * 16 + m16) * 128 + q * 8;
#pragma unroll
        for (int ks = 0; ks < 4; ++ks) bf[nt][ks] = *(const short8*)(wp + ks * 32);
    }
    const ushort* ap[4];
#pragma unroll
    for (int mt = 0; mt < 4; ++mt) {
        int r = m0 + mt * 16 + m16;
        if (r > n - 1) r = n - 1;
        ap[mt] = A + (size_t)r * 128 + q * 8;
    }

    f32x4 z = {0.f, 0.f, 0.f, 0.f};
    f32x4 acc[4][4];
#pragma unroll
    for (int mt = 0; mt < 4; ++mt)
#pragma unroll
        for (int nt = 0; nt < 4; ++nt) acc[mt][nt] = z;

#pragma unroll
    for (int ks = 0; ks < 4; ++ks) {
        short8 af[4];
#pragma unroll
        for (int mt = 0; mt < 4; ++mt) af[mt] = *(const short8*)(ap[mt] + ks * 32);
#pragma unroll
        for (int mt = 0; mt < 4; ++mt)
#pragma unroll
            for (int nt = 0; nt < 4; ++nt)
                acc[mt][nt] = __builtin_amdgcn_mfma_f32_16x16x32_bf16(
                    bf[nt][ks], af[mt], acc[mt][nt], 0, 0, 0);
    }

    ushort* outp = (wv >= 2) ? xrb : xlb;
    const float* bx = (wv >= 2) ? br : bl;
    int fb = (wv & 1) * 64;
#pragma unroll
    for (int nt = 0; nt < 4; ++nt) {
        int fcol = fb + nt * 16 + q * 4;
        float4 b4 = *(const float4*)&bx[fcol];
#pragma unroll
        for (int mt = 0; mt < 4; ++mt) {
            int m = m0 + mt * 16 + m16;
            if (m < n) {
                uint2 pk;
                pk.x = __builtin_bit_cast(uint, pkh(acc[mt][nt][0] + b4.x,
                                                    acc[mt][nt][1] + b4.y));
                pk.y = __builtin_bit_cast(uint, pkh(acc[mt][nt][2] + b4.z,
                                                    acc[mt][nt][3] + b4.w));
                *(uint2*)&outp[(size_t)m * 128 + fcol] = pk;
            }
        }
    }
}

__global__ __launch_bounds__(256) void csr_gemm0_kernel(
    const int* __restrict__ bptr, const uint* __restrict__ bbuf, int n,
    int* __restrict__ row_start, int* __restrict__ ssrc,
    const ushort* __restrict__ A, const ushort* __restrict__ Wt,
    const float* __restrict__ bl, const float* __restrict__ br,
    ushort* __restrict__ xlb, ushort* __restrict__ xrb) {
    int t = threadIdx.x;
    if (blockIdx.x >= NB) {
        gemm_body(A, Wt, bl, br, xlb, xrb, n, blockIdx.x - NB, t);
        return;
    }
    int b = blockIdx.x;
    __shared__ int sb[256], h[256], hx[256], lofs[256];
    int bv = (t < NB) ? min(bptr[t], BCAP) : 0;
    sb[t] = bv;
    __syncthreads();
    for (int off = 1; off < 256; off <<= 1) {
        int u = (t >= off) ? sb[t - off] : 0;
        __syncthreads();
        sb[t] += u;
        __syncthreads();
    }
    int cnt = min(bptr[b], BCAP);
    int base = sb[b] - cnt;               // exclusive prefix
    if (b == NB - 1 && t == 0) row_start[n] = sb[NB - 1];
    h[t] = 0; lofs[t] = 0;
    __syncthreads();
    const uint* bp = bbuf + (size_t)b * BCAP;
    for (int k = t; k < cnt; k += 256) atomicAdd(&h[bp[k] & 255u], 1);
    __syncthreads();
    int hv = h[t];
    hx[t] = hv;
    __syncthreads();
    for (int off = 1; off < 256; off <<= 1) {
        int u = (t >= off) ? hx[t - off] : 0;
        __syncthreads();
        hx[t] += u;
        __syncthreads();
    }
    int excl = hx[t] - hv;
    int node = (b << 8) + t;
    if (node < n) row_start[node] = base + excl;
    __syncthreads();
    h[t] = excl;
    __syncthreads();
    for (int k = t; k < cnt; k += 256) {
        uint val = bp[k];
        int dl = val & 255u;
        int pos = base + h[dl] + atomicAdd(&lofs[dl], 1);
        ssrc[pos] = (int)((val & 0xffff0000u) >> 8);   // src*256 byte offset
    }
}

__global__ __launch_bounds__(256) void gemm_mfma(
    const ushort* __restrict__ A, const ushort* __restrict__ Wt,
    const float* __restrict__ bl, const float* __restrict__ br,
    ushort* __restrict__ xlb, ushort* __restrict__ xrb, int n) {
    gemm_body(A, Wt, bl, br, xlb, xrb, n, blockIdx.x, threadIdx.x);
}

// ---------------- fused attention: packed-f16 datapath + packed shuffle reduce -------
// xl/xr fp16 pairs. Scores carry a built-in -8 shift (EINIT -0.5/lane, 8-lane head
// sum) so exp2 weights <= 0.25 and f16 den/acc cannot overflow; the 2^-8 cancels in
// the softmax division. Edge-pair scores are packed into one h2 -> 3 shfl per pair.

#define SLOTE(u, u01, u23, eh)                             \
    h2 u01 = __builtin_bit_cast(h2, u.x);                  \
    h2 u23 = __builtin_bit_cast(h2, u.y);                  \
    h2 eh;                                                 \
    {                                                      \
        h2 t01 = u01 + xr01, t23 = u23 + xr23;             \
        t01 = __builtin_elementwise_max(t01, t01 * K02);   \
        t23 = __builtin_elementwise_max(t23, t23 * K02);   \
        eh = EINIT + at01 * t01;                           \
        eh += at23 * t23;                                  \
    }

__device__ inline uint packpair(h2 a, h2 b) {   // -> (a.x+a.y, b.x+b.y)
    h2 lo = {a.x, b.x};
    h2 hi = {a.y, b.y};
    return __builtin_bit_cast(uint, lo + hi);
}
__device__ inline uint shfl_add_h2(uint q, int m) {
    uint r = (uint)__shfl_xor((int)q, m);
    h2 s = __builtin_bit_cast(h2, q) + __builtin_bit_cast(h2, r);
    return __builtin_bit_cast(uint, s);
}

__global__ __launch_bounds__(256) void attn_kernel(
    const uint* __restrict__ xlb, const uint* __restrict__ xrb,
    const float* __restrict__ att, const float* __restrict__ bias,
    const int* __restrict__ row_start, const int* __restrict__ ssrc,
    uint* __restrict__ hout, int n) {
    int wave = threadIdx.x >> 6;
    int lane = threadIdx.x & 63;
    int half = lane >> 5;
    int l32  = lane & 31;
    int i = blockIdx.x * 4 + wave;
    if (i >= n) return;

    const char* xlB = (const char*)xlb;
    int lofs = l32 * 8;

    uint2 xru = *(const uint2*)((const char*)xrb + (size_t)i * 256 + lofs);
    h2 xr01 = __builtin_bit_cast(h2, xru.x);
    h2 xr23 = __builtin_bit_cast(h2, xru.y);
    const float L2E = 1.4426950408889634f;
    float4 at = ((const float4*)att)[l32];
    h2 at01 = pkh(at.x * L2E, at.y * L2E);
    h2 at23 = pkh(at.z * L2E, at.w * L2E);
    const h2 K02   = {(_Float16)0.2f, (_Float16)0.2f};
    const h2 EINIT = {(_Float16)-0.5f, (_Float16)-0.5f};

    int p0 = row_start[i], p1 = row_start[i + 1];

    h2 denP = {0, 0};
    h2 aA01 = {0, 0}, aA23 = {0, 0};      // slots 0,2 (weighted by w01.x / w23.x)
    h2 aB01 = {0, 0}, aB23 = {0, 0};      // slots 1,3

    int p = p0;
    for (; p + 8 <= p1; p += 8) {          // 8 edges: 4 gathers in flight
        uint s0 = (uint)ssrc[p + half];
        uint s1 = (uint)ssrc[p + 2 + half];
        uint s2 = (uint)ssrc[p + 4 + half];
        uint s3 = (uint)ssrc[p + 6 + half];
        uint2 u0 = *(const uint2*)(xlB + (size_t)s0 + lofs);
        uint2 u1 = *(const uint2*)(xlB + (size_t)s1 + lofs);
        uint2 u2 = *(const uint2*)(xlB + (size_t)s2 + lofs);
        uint2 u3 = *(const uint2*)(xlB + (size_t)s3 + lofs);
        SLOTE(u0, v001, v023, eh0);
        SLOTE(u1, v101, v123, eh1);
        SLOTE(u2, v201, v223, eh2);
        SLOTE(u3, v301, v323, eh3);
        uint q01 = packpair(eh0, eh1);
        uint q23 = packpair(eh2, eh3);
        q01 = shfl_add_h2(q01, 1); q23 = shfl_add_h2(q23, 1);
        q01 = shfl_add_h2(q01, 2); q23 = shfl_add_h2(q23, 2);
        q01 = shfl_add_h2(q01, 4); q23 = shfl_add_h2(q23, 4);
        h2 e01 = __builtin_bit_cast(h2, q01);
        h2 e23 = __builtin_bit_cast(h2, q23);
        h2 w01, w23;
        w01.x = __ocml_exp2_f16(e01.x); w01.y = __ocml_exp2_f16(e01.y);
        w23.x = __ocml_exp2_f16(e23.x); w23.y = __ocml_exp2_f16(e23.y);
        denP += w01; denP += w23;
        h2 wA = {w01.x, w01.x}, wB = {w01.y, w01.y};
        h2 wC = {w23.x, w23.x}, wD = {w23.y, w23.y};
        aA01 += wA * v001; aA23 += wA * v023;
        aB01 += wB * v101; aB23 += wB * v123;
        aA01 += wC * v201; aA23 += wC * v223;
        aB01 += wD * v301; aB23 += wD * v323;
    }
    if (p < p1) {                           // masked epilogue: 1..7 edges
        int lst = p1 - 1;
        int i0 = p + half, i1 = p + 2 + half, i2 = p + 4 + half, i3 = p + 6 + half;
        uint s0 = (uint)ssrc[min(i0, lst)];
        uint s1 = (uint)ssrc[min(i1, lst)];
        uint s2 = (uint)ssrc[min(i2, lst)];
        uint s3 = (uint)ssrc[min(i3, lst)];
        uint2 u0 = *(const uint2*)(xlB + (size_t)s0 + lofs);
        uint2 u1 = *(const uint2*)(xlB + (size_t)s1 + lofs);
        uint2 u2 = *(const uint2*)(xlB + (size_t)s2 + lofs);
        uint2 u3 = *(const uint2*)(xlB + (size_t)s3 + lofs);
        SLOTE(u0, v001, v023, eh0);
        SLOTE(u1, v101, v123, eh1);
        SLOTE(u2, v201, v223, eh2);
        SLOTE(u3, v301, v323, eh3);
        uint q01 = packpair(eh0, eh1);
        uint q23 = packpair(eh2, eh3);
        q01 = shfl_add_h2(q01, 1); q23 = shfl_add_h2(q23, 1);
        q01 = shfl_add_h2(q01, 2); q23 = shfl_add_h2(q23, 2);
        q01 = shfl_add_h2(q01, 4); q23 = shfl_add_h2(q23, 4);
        h2 e01 = __builtin_bit_cast(h2, q01);
        h2 e23 = __builtin_bit_cast(h2, q23);
        h2 w01, w23;
        const _Float16 zh = (_Float16)0.f;
        w01.x = (i0 < p1) ? __ocml_exp2_f16(e01.x) : zh;
        w01.y = (i1 < p1) ? __ocml_exp2_f16(e01.y) : zh;
        w23.x = (i2 < p1) ? __ocml_exp2_f16(e23.x) : zh;
        w23.y = (i3 < p1) ? __ocml_exp2_f16(e23.y) : zh;
        denP += w01; denP += w23;
        h2 wA = {w01.x, w01.x}, wB = {w01.y, w01.y};
        h2 wC = {w23.x, w23.x}, wD = {w23.y, w23.y};
        aA01 += wA * v001; aA23 += wA * v023;
        aB01 += wB * v101; aB23 += wB * v123;
        aA01 += wC * v201; aA23 += wC * v223;
        aB01 += wD * v301; aB23 += wD * v323;
    }

    float den = (float)denP.x + (float)denP.y;
    float a0 = (float)(_Float16)(aA01.x + aB01.x);
    float a1 = (float)(_Float16)(aA01.y + aB01.y);
    float a2 = (float)(_Float16)(aA23.x + aB23.x);
    float a3 = (float)(_Float16)(aA23.y + aB23.y);
    den += __shfl_xor(den, 32);
    a0 += __shfl_xor(a0, 32);
    a1 += __shfl_xor(a1, 32);
    a2 += __shfl_xor(a2, 32);
    a3 += __shfl_xor(a3, 32);

    if (half == 0) {
        float inv = 1.f / den;
        float4 bi = ((const float4*)bias)[l32];
        float o0 = a0 * inv + bi.x; o0 = o0 > 0.f ? o0 : __expf(o0) - 1.f;
        float o1 = a1 * inv + bi.y; o1 = o1 > 0.f ? o1 : __expf(o1) - 1.f;
        float o2 = a2 * inv + bi.z; o2 = o2 > 0.f ? o2 : __expf(o2) - 1.f;
        float o3 = a3 * inv + bi.w; o3 = o3 > 0.f ? o3 : __expf(o3) - 1.f;
        uint2 pk;
        pk.x = pk2bf(o0, o1);
        pk.y = pk2bf(o2, o3);
        *(uint2*)((char*)hout + (size_t)i * 256 + lofs) = pk;
    }
}

// ---------------- pooling: (graph, split) grid, LDS reduce, few atomics ----------------

__device__ inline float bflo(uint v) { return __builtin_bit_cast(float, v << 16); }
__device__ inline float bfhi(uint v) { return __builtin_bit_cast(float, v & 0xffff0000u); }

__global__ __launch_bounds__(256) void pool_kernel(const uint* __restrict__ h2v,
                                                   const int* __restrict__ batch, int n,
                                                   float* __restrict__ psum) {
    int g = blockIdx.x;
    int t = threadIdx.x;
    int cp = t & 63;
    int sub = (t >> 6) | (blockIdx.y << 2);   // 0..31
    int b, e;
    {
        int lo = 0, hi = n;
        while (lo < hi) { int mid = (lo + hi) >> 1; if (batch[mid] < g) lo = mid + 1; else hi = mid; }
        b = lo;
        lo = 0; hi = n;
        int g1 = g + 1;
        while (lo < hi) { int mid = (lo + hi) >> 1; if (batch[mid] < g1) lo = mid + 1; else hi = mid; }
        e = lo;
    }
    float a0 = 0.f, a1 = 0.f;
    for (int i = b + sub; i < e; i += 32) {
        uint u = h2v[(size_t)i * 64 + cp];
        a0 += bflo(u); a1 += bfhi(u);
    }
    __shared__ float r0[256], r1[256];
    r0[t] = a0; r1[t] = a1;
    __syncthreads();
    if (t < 64) {
        float s0 = r0[t] + r0[t + 64] + r0[t + 128] + r0[t + 192];
        float s1 = r1[t] + r1[t + 64] + r1[t + 128] + r1[t + 192];
        atomicAdd(&psum[g * 128 + 2 * t], s0);
        atomicAdd(&psum[g * 128 + 2 * t + 1], s1);
    }
}

__global__ void final_kernel(const float* __restrict__ psum, const int* __restrict__ batch,
                             int n, const float* __restrict__ lw,
                             const float* __restrict__ lb, float* __restrict__ out) {
    int g = threadIdx.x;
    if (g >= N_GRAPHS) return;
    int b, e;
    {
        int lo = 0, hi = n;
        while (lo < hi) { int mid = (lo + hi) >> 1; if (batch[mid] < g) lo = mid + 1; else hi = mid; }
        b = lo;
        lo = 0; hi = n;
        int g1 = g + 1;
        while (lo < hi) { int mid = (lo + hi) >> 1; if (batch[mid] < g1) lo = mid + 1; else hi = mid; }
        e = lo;
    }
    float invc = 1.f / fmaxf((float)(e - b), 1.f);
    float z[N_CLASSES];
#pragma unroll
    for (int c = 0; c < N_CLASSES; ++c) z[c] = lb[c];
    for (int k = 0; k < 128; ++k) {
        float p = psum[g * 128 + k] * invc;
#pragma unroll
        for (int c = 0; c < N_CLASSES; ++c) z[c] += p * lw[k * N_CLASSES + c];
    }
    float mx = -1e30f;
#pragma unroll
    for (int c = 0; c < N_CLASSES; ++c) {
        z[c] = z[c] > 0.f ? z[c] : expf(z[c]) - 1.f;
        mx = fmaxf(mx, z[c]);
    }
    float s = 0.f;
#pragma unroll
    for (int c = 0; c < N_CLASSES; ++c) s += expf(z[c] - mx);
    float lse = mx + logf(s);
#pragma unroll
    for (int c = 0; c < N_CLASSES; ++c) out[g * N_CLASSES + c] = z[c] - lse;
}

// ---------------- launch ----------------

extern "C" void kernel_launch(void* const* d_in, const int* in_sizes, int n_in,
                              void* d_out, int out_size, void* d_ws, size_t ws_size,
                              hipStream_t stream) {
    const float* x     = (const float*)d_in[0];
    const int*   ei    = (const int*)d_in[1];
    const int*   batch = (const int*)d_in[2];
    const float* Wl    = (const float*)d_in[3];
    const float* Wr    = (const float*)d_in[4];
    const float* bl    = (const float*)d_in[5];
    const float* br    = (const float*)d_in[6];
    const float* att   = (const float*)d_in[7];
    const float* bias  = (const float*)d_in[8];
    const float* lw    = (const float*)d_in[9];
    const float* lb    = (const float*)d_in[10];
    float* out = (float*)d_out;

    const int n = in_sizes[2];         // 50000
    const int E = in_sizes[1] / 2;     // 800000
    const int total_edges = E + n;

    char* ws = (char*)d_ws;
    size_t o = 0;
    auto alloc = [&](size_t bytes) -> void* {
        void* p = ws + o;
        o = (o + bytes + 255) & ~(size_t)255;
        return p;
    };
    int*    row_start = (int*)alloc((size_t)(n + 1) * 4);
    int*    bptr      = (int*)alloc((size_t)NB * 4);
    uint*   bbuf      = (uint*)alloc((size_t)NB * BCAP * 4);
    int*    ssrc      = (int*)alloc((size_t)total_edges * 4);
    ushort* xbf0      = (ushort*)alloc((size_t)n * HID * 2);
    ushort* xlb       = (ushort*)alloc((size_t)n * HID * 2);
    ushort* xrb       = (ushort*)alloc((size_t)n * HID * 2);
    ushort* hbA       = (ushort*)alloc((size_t)n * HID * 2);
    ushort* hbB       = (ushort*)alloc((size_t)n * HID * 2);
    uint*   wt        = (uint*)alloc((size_t)N_LAYERS * 256 * 64 * 4);
    float*  psum      = (float*)alloc((size_t)N_GRAPHS * HID * 4);

    hipMemsetAsync(bptr, 0, (size_t)NB * 4, stream);
    hipMemsetAsync(psum, 0, (size_t)N_GRAPHS * HID * 4, stream);

    int wtot = N_LAYERS * 256 * 64;
    int xqb = (n * 16 + 255) / 256;                       // 3125
    int wb  = (wtot + 255) / 256;                         // 192
    int pb  = (total_edges + ACHUNK - 1) / ACHUNK;        // 208
    setup_kernel<<<xqb + wb + pb, 256, 0, stream>>>(
        x, (uint*)xbf0, n, Wl, Wr, wt, wtot, ei, E, bptr, bbuf, xqb, wb);

    int mblocks = (n + 63) / 64;
    int ablocks = (n + 3) / 4;

    csr_gemm0_kernel<<<NB + mblocks, 256, 0, stream>>>(
        bptr, bbuf, n, row_start, ssrc,
        xbf0, (const ushort*)wt, bl, br, xlb, xrb);

    attn_kernel<<<ablocks, 256, 0, stream>>>((const uint*)xlb, (const uint*)xrb,
                                             att, bias, row_start, ssrc, (uint*)hbA, n);
    gemm_mfma<<<mblocks, 256, 0, stream>>>(hbA, (const ushort*)(wt + (size_t)256 * 64),
                                           bl + HID, br + HID, xlb, xrb, n);
    attn_kernel<<<ablocks, 256, 0, stream>>>((const uint*)xlb, (const uint*)xrb,
                                             att + HID, bias + HID, row_start, ssrc,
                                             (uint*)hbB, n);
    gemm_mfma<<<mblocks, 256, 0, stream>>>(hbB, (const ushort*)(wt + (size_t)2 * 256 * 64),
                                           bl + 2 * HID, br + 2 * HID, xlb, xrb, n);
    attn_kernel<<<ablocks, 256, 0, stream>>>((const uint*)xlb, (const uint*)xrb,
                                             att + 2 * HID, bias + 2 * HID, row_start, ssrc,
                                             (uint*)hbA, n);

    pool_kernel<<<dim3(N_GRAPHS, 8), 256, 0, stream>>>((const uint*)hbA, batch, n, psum);
    final_kernel<<<1, 64, 0, stream>>>(psum, batch, n, lw, lb, out);
}

// Round 13
// 332.619 us; speedup vs baseline: 1.0554x; 1.0117x over previous
//
#include <hip/hip_runtime.h>
#include <hip/hip_bf16.h>
#include <math.h>

#define N_NODES 50000
#define N_EDGES 800000
#define N_GRAPHS 64
#define HID 128
#define N_CLASSES 10
#define N_LAYERS 3
#define NEG_SLOPE 0.2f

#define NB 196        // dst buckets of 256 nodes
#define BCAP 5120     // slots per bucket (mean ~4337, sigma ~66 -> +12 sigma)
#define ACHUNK 4096   // edges per partition block

typedef __attribute__((ext_vector_type(8))) short short8;
typedef __attribute__((ext_vector_type(4))) float f32x4;
typedef __attribute__((ext_vector_type(2))) _Float16 h2;

extern "C" __device__ _Float16 __ocml_exp2_f16(_Float16);

__device__ inline ushort f2bf(float f) {
    uint u = __builtin_bit_cast(uint, f);
    u += 0x7fffu + ((u >> 16) & 1u);      // RNE
    return (ushort)(u >> 16);
}
__device__ inline uint pk2bf(float a, float b) {
    return (uint)f2bf(a) | ((uint)f2bf(b) << 16);
}
__device__ inline h2 pkh(float a, float b) {
    return __builtin_bit_cast(h2, __builtin_amdgcn_cvt_pkrtz(a, b));
}

// ---------------- setup: x/W bf16 prep + edge partition, one launch ----------------

__global__ __launch_bounds__(256) void setup_kernel(
    const float* __restrict__ x, uint* __restrict__ xb, int n,
    const float* __restrict__ Wl, const float* __restrict__ Wr,
    uint* __restrict__ wt, int wtot,
    const int* __restrict__ ei, int E,
    int* __restrict__ bptr, uint* __restrict__ bbuf,
    int xqb, int wb) {
    __shared__ int hcnt[256];
    __shared__ int hexcl[256];
    __shared__ int lofs[256];
    __shared__ int delta[256];
    __shared__ uint stage[ACHUNK];
    int t = threadIdx.x;
    int blk = blockIdx.x;

    if (blk < xqb) {                      // ---- x prep: 1 uint4 (8 floats) per thread
        int j = blk * 256 + t;
        if (j < n * 16) {
            const float4* xp = (const float4*)x + (size_t)j * 2;
            float4 a = xp[0], b = xp[1];
            uint4 o;
            o.x = pk2bf(a.x, a.y); o.y = pk2bf(a.z, a.w);
            o.z = pk2bf(b.x, b.y); o.w = pk2bf(b.z, b.w);
            ((uint4*)xb)[j] = o;
        }
        return;
    }
    blk -= xqb;
    if (blk < wb) {                       // ---- W prep (bf16)
        int i = blk * 256 + t;
        if (i >= wtot) return;
        int kp = i & 63;
        int nn = (i >> 6) & 255;
        int l  = i >> 14;
        const float* W = (nn < 128) ? Wl : Wr;
        int c = nn & 127;
        wt[i] = pk2bf(W[l * 16384 + (2 * kp) * 128 + c],
                      W[l * 16384 + (2 * kp + 1) * 128 + c]);
        return;
    }
    blk -= wb;                            // ---- partition
    int total = E + n;
    int base = blk * ACHUNK;
    int cntblk = min(ACHUNK, total - base);
    hcnt[t] = 0; lofs[t] = 0;
    __syncthreads();

    uint v[16]; int bk[16];
#pragma unroll
    for (int j = 0; j < 16; ++j) {
        int e = base + j * 256 + t;
        bk[j] = -1;
        if (e < total) {
            int s, d;
            if (e < E) { s = ei[e]; d = ei[E + e]; }
            else       { s = e - E; d = e - E; }
            v[j] = ((uint)s << 16) | (uint)d;    // src,dst both < 65536
            bk[j] = d >> 8;
            atomicAdd(&hcnt[bk[j]], 1);
        }
    }
    __syncthreads();
    int hv = hcnt[t];
    __shared__ int stmp[256];
    stmp[t] = hv;
    __syncthreads();
    for (int off = 1; off < 256; off <<= 1) {
        int u = (t >= off) ? stmp[t - off] : 0;
        __syncthreads();
        stmp[t] += u;
        __syncthreads();
    }
    hexcl[t] = stmp[t] - hv;
    __syncthreads();
#pragma unroll
    for (int j = 0; j < 16; ++j) {
        if (bk[j] >= 0) {
            int pos = hexcl[bk[j]] + atomicAdd(&lofs[bk[j]], 1);
            stage[pos] = v[j];
        }
    }
    __syncthreads();
    if (t < NB) {
        int c = hcnt[t];
        int gb = c ? atomicAdd(&bptr[t], c) : 0;
        delta[t] = t * BCAP + gb - hexcl[t];
    }
    __syncthreads();
    for (int idx = t; idx < cntblk; idx += 256) {
        uint val = stage[idx];
        int b = (val >> 8) & 0xff;
        int tgt = delta[b] + idx;
        if (tgt < (b + 1) * BCAP) bbuf[tgt] = val;
    }
}

// ---------------- bucket CSR (blocks 0..NB) + gemm layer 0 (rest), one launch --------
// gemm inputs A,W stay bf16; OUTPUT xl/xr is fp16 (consumed only by attn).

__device__ __forceinline__ void gemm_body(
    const ushort* __restrict__ A, const ushort* __restrict__ Wt,
    const float* __restrict__ bl, const float* __restrict__ br,
    ushort* __restrict__ xlb, ushort* __restrict__ xrb, int n, int bid, int tid) {
    int wv = tid >> 6;
    int lane = tid & 63;
    int q = lane >> 4, m16 = lane & 15;
    int m0 = bid * 64;

    short8 bf[4][4];
#pragma unroll
    for (int nt = 0; nt < 4; ++nt) {
        const ushort* wp = Wt + (size_t)(wv * 64 + nt * 16 + m16) * 128 + q * 8;
#pragma unroll
        for (int ks = 0; ks < 4; ++ks) bf[nt][ks] = *(const short8*)(wp + ks * 32);
    }
    const ushort* ap[4];
#pragma unroll
    for (int mt = 0; mt < 4; ++mt) {
        int r = m0 + mt * 16 + m16;
        if (r > n - 1) r = n - 1;
        ap[mt] = A + (size_t)r * 128 + q * 8;
    }

    f32x4 z = {0.f, 0.f, 0.f, 0.f};
    f32x4 acc[4][4];
#pragma unroll
    for (int mt = 0; mt < 4; ++mt)
#pragma unroll
        for (int nt = 0; nt < 4; ++nt) acc[mt][nt] = z;

#pragma unroll
    for (int ks = 0; ks < 4; ++ks) {
        short8 af[4];
#pragma unroll
        for (int mt = 0; mt < 4; ++mt) af[mt] = *(const short8*)(ap[mt] + ks * 32);
#pragma unroll
        for (int mt = 0; mt < 4; ++mt)
#pragma unroll
            for (int nt = 0; nt < 4; ++nt)
                acc[mt][nt] = __builtin_amdgcn_mfma_f32_16x16x32_bf16(
                    bf[nt][ks], af[mt], acc[mt][nt], 0, 0, 0);
    }

    ushort* outp = (wv >= 2) ? xrb : xlb;
    const float* bx = (wv >= 2) ? br : bl;
    int fb = (wv & 1) * 64;
#pragma unroll
    for (int nt = 0; nt < 4; ++nt) {
        int fcol = fb + nt * 16 + q * 4;
        float4 b4 = *(const float4*)&bx[fcol];
#pragma unroll
        for (int mt = 0; mt < 4; ++mt) {
            int m = m0 + mt * 16 + m16;
            if (m < n) {
                uint2 pk;
                pk.x = __builtin_bit_cast(uint, pkh(acc[mt][nt][0] + b4.x,
                                                    acc[mt][nt][1] + b4.y));
                pk.y = __builtin_bit_cast(uint, pkh(acc[mt][nt][2] + b4.z,
                                                    acc[mt][nt][3] + b4.w));
                *(uint2*)&outp[(size_t)m * 128 + fcol] = pk;
            }
        }
    }
}

__global__ __launch_bounds__(256) void csr_gemm0_kernel(
    const int* __restrict__ bptr, const uint* __restrict__ bbuf, int n,
    int* __restrict__ row_start, int* __restrict__ ssrc,
    const ushort* __restrict__ A, const ushort* __restrict__ Wt,
    const float* __restrict__ bl, const float* __restrict__ br,
    ushort* __restrict__ xlb, ushort* __restrict__ xrb) {
    int t = threadIdx.x;
    if (blockIdx.x >= NB) {
        gemm_body(A, Wt, bl, br, xlb, xrb, n, blockIdx.x - NB, t);
        return;
    }
    int b = blockIdx.x;
    __shared__ int sb[256], h[256], hx[256], lofs[256];
    int bv = (t < NB) ? min(bptr[t], BCAP) : 0;
    sb[t] = bv;
    __syncthreads();
    for (int off = 1; off < 256; off <<= 1) {
        int u = (t >= off) ? sb[t - off] : 0;
        __syncthreads();
        sb[t] += u;
        __syncthreads();
    }
    int cnt = min(bptr[b], BCAP);
    int base = sb[b] - cnt;               // exclusive prefix
    if (b == NB - 1 && t == 0) row_start[n] = sb[NB - 1];
    h[t] = 0; lofs[t] = 0;
    __syncthreads();
    const uint* bp = bbuf + (size_t)b * BCAP;
    for (int k = t; k < cnt; k += 256) atomicAdd(&h[bp[k] & 255u], 1);
    __syncthreads();
    int hv = h[t];
    hx[t] = hv;
    __syncthreads();
    for (int off = 1; off < 256; off <<= 1) {
        int u = (t >= off) ? hx[t - off] : 0;
        __syncthreads();
        hx[t] += u;
        __syncthreads();
    }
    int excl = hx[t] - hv;
    int node = (b << 8) + t;
    if (node < n) row_start[node] = base + excl;
    __syncthreads();
    h[t] = excl;
    __syncthreads();
    for (int k = t; k < cnt; k += 256) {
        uint val = bp[k];
        int dl = val & 255u;
        int pos = base + h[dl] + atomicAdd(&lofs[dl], 1);
        ssrc[pos] = (int)((val & 0xffff0000u) >> 8);   // src*256 byte offset
    }
}

__global__ __launch_bounds__(256) void gemm_mfma(
    const ushort* __restrict__ A, const ushort* __restrict__ Wt,
    const float* __restrict__ bl, const float* __restrict__ br,
    ushort* __restrict__ xlb, ushort* __restrict__ xrb, int n) {
    gemm_body(A, Wt, bl, br, xlb, xrb, n, blockIdx.x, threadIdx.x);
}

// ---------------- fused attention: packed-f16 datapath, 16-edge main loop -----------
// xl/xr fp16 pairs. Scores carry a built-in -8 shift (EINIT -0.5/lane, 8-lane head
// sum) so exp2 weights <= 0.25 and f16 den/acc cannot overflow; the 2^-8 cancels in
// the softmax division. 16 edges/iter -> 8 gathers in flight (latency probe).

#define SLOTE(u, u01, u23, eh)                             \
    h2 u01 = __builtin_bit_cast(h2, u.x);                  \
    h2 u23 = __builtin_bit_cast(h2, u.y);                  \
    h2 eh;                                                 \
    {                                                      \
        h2 t01 = u01 + xr01, t23 = u23 + xr23;             \
        t01 = __builtin_elementwise_max(t01, t01 * K02);   \
        t23 = __builtin_elementwise_max(t23, t23 * K02);   \
        eh = EINIT + at01 * t01;                           \
        eh += at23 * t23;                                  \
    }

__device__ inline uint packpair(h2 a, h2 b) {   // -> (a.x+a.y, b.x+b.y)
    h2 lo = {a.x, b.x};
    h2 hi = {a.y, b.y};
    return __builtin_bit_cast(uint, lo + hi);
}
__device__ inline uint shfl_add_h2(uint q, int m) {
    uint r = (uint)__shfl_xor((int)q, m);
    h2 s = __builtin_bit_cast(h2, q) + __builtin_bit_cast(h2, r);
    return __builtin_bit_cast(uint, s);
}

__global__ __launch_bounds__(256) void attn_kernel(
    const uint* __restrict__ xlb, const uint* __restrict__ xrb,
    const float* __restrict__ att, const float* __restrict__ bias,
    const int* __restrict__ row_start, const int* __restrict__ ssrc,
    uint* __restrict__ hout, int n) {
    int wave = threadIdx.x >> 6;
    int lane = threadIdx.x & 63;
    int half = lane >> 5;
    int l32  = lane & 31;
    int i = blockIdx.x * 4 + wave;
    if (i >= n) return;

    const char* xlB = (const char*)xlb;
    int lofs = l32 * 8;

    uint2 xru = *(const uint2*)((const char*)xrb + (size_t)i * 256 + lofs);
    h2 xr01 = __builtin_bit_cast(h2, xru.x);
    h2 xr23 = __builtin_bit_cast(h2, xru.y);
    const float L2E = 1.4426950408889634f;
    float4 at = ((const float4*)att)[l32];
    h2 at01 = pkh(at.x * L2E, at.y * L2E);
    h2 at23 = pkh(at.z * L2E, at.w * L2E);
    const h2 K02   = {(_Float16)0.2f, (_Float16)0.2f};
    const h2 EINIT = {(_Float16)-0.5f, (_Float16)-0.5f};

    int p0 = row_start[i], p1 = row_start[i + 1];

    h2 denP = {0, 0};
    h2 aA01 = {0, 0}, aA23 = {0, 0};      // even slots
    h2 aB01 = {0, 0}, aB23 = {0, 0};      // odd slots

    int p = p0;
    for (; p + 16 <= p1; p += 16) {        // 16 edges: 8 gathers in flight
        uint s0 = (uint)ssrc[p + half];
        uint s1 = (uint)ssrc[p + 2 + half];
        uint s2 = (uint)ssrc[p + 4 + half];
        uint s3 = (uint)ssrc[p + 6 + half];
        uint s4 = (uint)ssrc[p + 8 + half];
        uint s5 = (uint)ssrc[p + 10 + half];
        uint s6 = (uint)ssrc[p + 12 + half];
        uint s7 = (uint)ssrc[p + 14 + half];
        uint2 u0 = *(const uint2*)(xlB + (size_t)s0 + lofs);
        uint2 u1 = *(const uint2*)(xlB + (size_t)s1 + lofs);
        uint2 u2 = *(const uint2*)(xlB + (size_t)s2 + lofs);
        uint2 u3 = *(const uint2*)(xlB + (size_t)s3 + lofs);
        uint2 u4 = *(const uint2*)(xlB + (size_t)s4 + lofs);
        uint2 u5 = *(const uint2*)(xlB + (size_t)s5 + lofs);
        uint2 u6 = *(const uint2*)(xlB + (size_t)s6 + lofs);
        uint2 u7 = *(const uint2*)(xlB + (size_t)s7 + lofs);
        SLOTE(u0, v001, v023, eh0);
        SLOTE(u1, v101, v123, eh1);
        SLOTE(u2, v201, v223, eh2);
        SLOTE(u3, v301, v323, eh3);
        SLOTE(u4, v401, v423, eh4);
        SLOTE(u5, v501, v523, eh5);
        SLOTE(u6, v601, v623, eh6);
        SLOTE(u7, v701, v723, eh7);
        uint q01 = packpair(eh0, eh1);
        uint q23 = packpair(eh2, eh3);
        uint q45 = packpair(eh4, eh5);
        uint q67 = packpair(eh6, eh7);
        q01 = shfl_add_h2(q01, 1); q23 = shfl_add_h2(q23, 1);
        q45 = shfl_add_h2(q45, 1); q67 = shfl_add_h2(q67, 1);
        q01 = shfl_add_h2(q01, 2); q23 = shfl_add_h2(q23, 2);
        q45 = shfl_add_h2(q45, 2); q67 = shfl_add_h2(q67, 2);
        q01 = shfl_add_h2(q01, 4); q23 = shfl_add_h2(q23, 4);
        q45 = shfl_add_h2(q45, 4); q67 = shfl_add_h2(q67, 4);
        h2 e01 = __builtin_bit_cast(h2, q01);
        h2 e23 = __builtin_bit_cast(h2, q23);
        h2 e45 = __builtin_bit_cast(h2, q45);
        h2 e67 = __builtin_bit_cast(h2, q67);
        h2 w01, w23, w45, w67;
        w01.x = __ocml_exp2_f16(e01.x); w01.y = __ocml_exp2_f16(e01.y);
        w23.x = __ocml_exp2_f16(e23.x); w23.y = __ocml_exp2_f16(e23.y);
        w45.x = __ocml_exp2_f16(e45.x); w45.y = __ocml_exp2_f16(e45.y);
        w67.x = __ocml_exp2_f16(e67.x); w67.y = __ocml_exp2_f16(e67.y);
        denP += w01; denP += w23; denP += w45; denP += w67;
        h2 wA = {w01.x, w01.x}, wB = {w01.y, w01.y};
        h2 wC = {w23.x, w23.x}, wD = {w23.y, w23.y};
        h2 wE = {w45.x, w45.x}, wF = {w45.y, w45.y};
        h2 wG = {w67.x, w67.x}, wH = {w67.y, w67.y};
        aA01 += wA * v001; aA23 += wA * v023;
        aB01 += wB * v101; aB23 += wB * v123;
        aA01 += wC * v201; aA23 += wC * v223;
        aB01 += wD * v301; aB23 += wD * v323;
        aA01 += wE * v401; aA23 += wE * v423;
        aB01 += wF * v501; aB23 += wF * v523;
        aA01 += wG * v601; aA23 += wG * v623;
        aB01 += wH * v701; aB23 += wH * v723;
    }
    for (; p + 8 <= p1; p += 8) {          // 8 edges: 4 gathers in flight
        uint s0 = (uint)ssrc[p + half];
        uint s1 = (uint)ssrc[p + 2 + half];
        uint s2 = (uint)ssrc[p + 4 + half];
        uint s3 = (uint)ssrc[p + 6 + half];
        uint2 u0 = *(const uint2*)(xlB + (size_t)s0 + lofs);
        uint2 u1 = *(const uint2*)(xlB + (size_t)s1 + lofs);
        uint2 u2 = *(const uint2*)(xlB + (size_t)s2 + lofs);
        uint2 u3 = *(const uint2*)(xlB + (size_t)s3 + lofs);
        SLOTE(u0, v001, v023, eh0);
        SLOTE(u1, v101, v123, eh1);
        SLOTE(u2, v201, v223, eh2);
        SLOTE(u3, v301, v323, eh3);
        uint q01 = packpair(eh0, eh1);
        uint q23 = packpair(eh2, eh3);
        q01 = shfl_add_h2(q01, 1); q23 = shfl_add_h2(q23, 1);
        q01 = shfl_add_h2(q01, 2); q23 = shfl_add_h2(q23, 2);
        q01 = shfl_add_h2(q01, 4); q23 = shfl_add_h2(q23, 4);
        h2 e01 = __builtin_bit_cast(h2, q01);
        h2 e23 = __builtin_bit_cast(h2, q23);
        h2 w01, w23;
        w01.x = __ocml_exp2_f16(e01.x); w01.y = __ocml_exp2_f16(e01.y);
        w23.x = __ocml_exp2_f16(e23.x); w23.y = __ocml_exp2_f16(e23.y);
        denP += w01; denP += w23;
        h2 wA = {w01.x, w01.x}, wB = {w01.y, w01.y};
        h2 wC = {w23.x, w23.x}, wD = {w23.y, w23.y};
        aA01 += wA * v001; aA23 += wA * v023;
        aB01 += wB * v101; aB23 += wB * v123;
        aA01 += wC * v201; aA23 += wC * v223;
        aB01 += wD * v301; aB23 += wD * v323;
    }
    if (p < p1) {                           // masked epilogue: 1..7 edges
        int lst = p1 - 1;
        int i0 = p + half, i1 = p + 2 + half, i2 = p + 4 + half, i3 = p + 6 + half;
        uint s0 = (uint)ssrc[min(i0, lst)];
        uint s1 = (uint)ssrc[min(i1, lst)];
        uint s2 = (uint)ssrc[min(i2, lst)];
        uint s3 = (uint)ssrc[min(i3, lst)];
        uint2 u0 = *(const uint2*)(xlB + (size_t)s0 + lofs);
        uint2 u1 = *(const uint2*)(xlB + (size_t)s1 + lofs);
        uint2 u2 = *(const uint2*)(xlB + (size_t)s2 + lofs);
        uint2 u3 = *(const uint2*)(xlB + (size_t)s3 + lofs);
        SLOTE(u0, v001, v023, eh0);
        SLOTE(u1, v101, v123, eh1);
        SLOTE(u2, v201, v223, eh2);
        SLOTE(u3, v301, v323, eh3);
        uint q01 = packpair(eh0, eh1);
        uint q23 = packpair(eh2, eh3);
        q01 = shfl_add_h2(q01, 1); q23 = shfl_add_h2(q23, 1);
        q01 = shfl_add_h2(q01, 2); q23 = shfl_add_h2(q23, 2);
        q01 = shfl_add_h2(q01, 4); q23 = shfl_add_h2(q23, 4);
        h2 e01 = __builtin_bit_cast(h2, q01);
        h2 e23 = __builtin_bit_cast(h2, q23);
        h2 w01, w23;
        const _Float16 zh = (_Float16)0.f;
        w01.x = (i0 < p1) ? __ocml_exp2_f16(e01.x) : zh;
        w01.y = (i1 < p1) ? __ocml_exp2_f16(e01.y) : zh;
        w23.x = (i2 < p1) ? __ocml_exp2_f16(e23.x) : zh;
        w23.y = (i3 < p1) ? __ocml_exp2_f16(e23.y) : zh;
        denP += w01; denP += w23;
        h2 wA = {w01.x, w01.x}, wB = {w01.y, w01.y};
        h2 wC = {w23.x, w23.x}, wD = {w23.y, w23.y};
        aA01 += wA * v001; aA23 += wA * v023;
        aB01 += wB * v101; aB23 += wB * v123;
        aA01 += wC * v201; aA23 += wC * v223;
        aB01 += wD * v301; aB23 += wD * v323;
    }

    float den = (float)denP.x + (float)denP.y;
    float a0 = (float)(_Float16)(aA01.x + aB01.x);
    float a1 = (float)(_Float16)(aA01.y + aB01.y);
    float a2 = (float)(_Float16)(aA23.x + aB23.x);
    float a3 = (float)(_Float16)(aA23.y + aB23.y);
    den += __shfl_xor(den, 32);
    a0 += __shfl_xor(a0, 32);
    a1 += __shfl_xor(a1, 32);
    a2 += __shfl_xor(a2, 32);
    a3 += __shfl_xor(a3, 32);

    if (half == 0) {
        float inv = 1.f / den;
        float4 bi = ((const float4*)bias)[l32];
        float o0 = a0 * inv + bi.x; o0 = o0 > 0.f ? o0 : __expf(o0) - 1.f;
        float o1 = a1 * inv + bi.y; o1 = o1 > 0.f ? o1 : __expf(o1) - 1.f;
        float o2 = a2 * inv + bi.z; o2 = o2 > 0.f ? o2 : __expf(o2) - 1.f;
        float o3 = a3 * inv + bi.w; o3 = o3 > 0.f ? o3 : __expf(o3) - 1.f;
        uint2 pk;
        pk.x = pk2bf(o0, o1);
        pk.y = pk2bf(o2, o3);
        *(uint2*)((char*)hout + (size_t)i * 256 + lofs) = pk;
    }
}

// ---------------- pooling: (graph, split) grid, LDS reduce, few atomics ----------------

__device__ inline float bflo(uint v) { return __builtin_bit_cast(float, v << 16); }
__device__ inline float bfhi(uint v) { return __builtin_bit_cast(float, v & 0xffff0000u); }

__global__ __launch_bounds__(256) void pool_kernel(const uint* __restrict__ h2v,
                                                   const int* __restrict__ batch, int n,
                                                   float* __restrict__ psum) {
    int g = blockIdx.x;
    int t = threadIdx.x;
    int cp = t & 63;
    int sub = (t >> 6) | (blockIdx.y << 2);   // 0..31
    int b, e;
    {
        int lo = 0, hi = n;
        while (lo < hi) { int mid = (lo + hi) >> 1; if (batch[mid] < g) lo = mid + 1; else hi = mid; }
        b = lo;
        lo = 0; hi = n;
        int g1 = g + 1;
        while (lo < hi) { int mid = (lo + hi) >> 1; if (batch[mid] < g1) lo = mid + 1; else hi = mid; }
        e = lo;
    }
    float a0 = 0.f, a1 = 0.f;
    for (int i = b + sub; i < e; i += 32) {
        uint u = h2v[(size_t)i * 64 + cp];
        a0 += bflo(u); a1 += bfhi(u);
    }
    __shared__ float r0[256], r1[256];
    r0[t] = a0; r1[t] = a1;
    __syncthreads();
    if (t < 64) {
        float s0 = r0[t] + r0[t + 64] + r0[t + 128] + r0[t + 192];
        float s1 = r1[t] + r1[t + 64] + r1[t + 128] + r1[t + 192];
        atomicAdd(&psum[g * 128 + 2 * t], s0);
        atomicAdd(&psum[g * 128 + 2 * t + 1], s1);
    }
}

__global__ void final_kernel(const float* __restrict__ psum, const int* __restrict__ batch,
                             int n, const float* __restrict__ lw,
                             const float* __restrict__ lb, float* __restrict__ out) {
    int g = threadIdx.x;
    if (g >= N_GRAPHS) return;
    int b, e;
    {
        int lo = 0, hi = n;
        while (lo < hi) { int mid = (lo + hi) >> 1; if (batch[mid] < g) lo = mid + 1; else hi = mid; }
        b = lo;
        lo = 0; hi = n;
        int g1 = g + 1;
        while (lo < hi) { int mid = (lo + hi) >> 1; if (batch[mid] < g1) lo = mid + 1; else hi = mid; }
        e = lo;
    }
    float invc = 1.f / fmaxf((float)(e - b), 1.f);
    float z[N_CLASSES];
#pragma unroll
    for (int c = 0; c < N_CLASSES; ++c) z[c] = lb[c];
    for (int k = 0; k < 128; ++k) {
        float p = psum[g * 128 + k] * invc;
#pragma unroll
        for (int c = 0; c < N_CLASSES; ++c) z[c] += p * lw[k * N_CLASSES + c];
    }
    float mx = -1e30f;
#pragma unroll
    for (int c = 0; c < N_CLASSES; ++c) {
        z[c] = z[c] > 0.f ? z[c] : expf(z[c]) - 1.f;
        mx = fmaxf(mx, z[c]);
    }
    float s = 0.f;
#pragma unroll
    for (int c = 0; c < N_CLASSES; ++c) s += expf(z[c] - mx);
    float lse = mx + logf(s);
#pragma unroll
    for (int c = 0; c < N_CLASSES; ++c) out[g * N_CLASSES + c] = z[c] - lse;
}

// ---------------- launch ----------------

extern "C" void kernel_launch(void* const* d_in, const int* in_sizes, int n_in,
                              void* d_out, int out_size, void* d_ws, size_t ws_size,
                              hipStream_t stream) {
    const float* x     = (const float*)d_in[0];
    const int*   ei    = (const int*)d_in[1];
    const int*   batch = (const int*)d_in[2];
    const float* Wl    = (const float*)d_in[3];
    const float* Wr    = (const float*)d_in[4];
    const float* bl    = (const float*)d_in[5];
    const float* br    = (const float*)d_in[6];
    const float* att   = (const float*)d_in[7];
    const float* bias  = (const float*)d_in[8];
    const float* lw    = (const float*)d_in[9];
    const float* lb    = (const float*)d_in[10];
    float* out = (float*)d_out;

    const int n = in_sizes[2];         // 50000
    const int E = in_sizes[1] / 2;     // 800000
    const int total_edges = E + n;

    char* ws = (char*)d_ws;
    size_t o = 0;
    auto alloc = [&](size_t bytes) -> void* {
        void* p = ws + o;
        o = (o + bytes + 255) & ~(size_t)255;
        return p;
    };
    int*    row_start = (int*)alloc((size_t)(n + 1) * 4);
    int*    bptr      = (int*)alloc((size_t)NB * 4);
    uint*   bbuf      = (uint*)alloc((size_t)NB * BCAP * 4);
    int*    ssrc      = (int*)alloc((size_t)total_edges * 4);
    ushort* xbf0      = (ushort*)alloc((size_t)n * HID * 2);
    ushort* xlb       = (ushort*)alloc((size_t)n * HID * 2);
    ushort* xrb       = (ushort*)alloc((size_t)n * HID * 2);
    ushort* hbA       = (ushort*)alloc((size_t)n * HID * 2);
    ushort* hbB       = (ushort*)alloc((size_t)n * HID * 2);
    uint*   wt        = (uint*)alloc((size_t)N_LAYERS * 256 * 64 * 4);
    float*  psum      = (float*)alloc((size_t)N_GRAPHS * HID * 4);

    hipMemsetAsync(bptr, 0, (size_t)NB * 4, stream);
    hipMemsetAsync(psum, 0, (size_t)N_GRAPHS * HID * 4, stream);

    int wtot = N_LAYERS * 256 * 64;
    int xqb = (n * 16 + 255) / 256;                       // 3125
    int wb  = (wtot + 255) / 256;                         // 192
    int pb  = (total_edges + ACHUNK - 1) / ACHUNK;        // 208
    setup_kernel<<<xqb + wb + pb, 256, 0, stream>>>(
        x, (uint*)xbf0, n, Wl, Wr, wt, wtot, ei, E, bptr, bbuf, xqb, wb);

    int mblocks = (n + 63) / 64;
    int ablocks = (n + 3) / 4;

    csr_gemm0_kernel<<<NB + mblocks, 256, 0, stream>>>(
        bptr, bbuf, n, row_start, ssrc,
        xbf0, (const ushort*)wt, bl, br, xlb, xrb);

    attn_kernel<<<ablocks, 256, 0, stream>>>((const uint*)xlb, (const uint*)xrb,
                                             att, bias, row_start, ssrc, (uint*)hbA, n);
    gemm_mfma<<<mblocks, 256, 0, stream>>>(hbA, (const ushort*)(wt + (size_t)256 * 64),
                                           bl + HID, br + HID, xlb, xrb, n);
    attn_kernel<<<ablocks, 256, 0, stream>>>((const uint*)xlb, (const uint*)xrb,
                                             att + HID, bias + HID, row_start, ssrc,
                                             (uint*)hbB, n);
    gemm_mfma<<<mblocks, 256, 0, stream>>>(hbB, (const ushort*)(wt + (size_t)2 * 256 * 64),
                                           bl + 2 * HID, br + 2 * HID, xlb, xrb, n);
    attn_kernel<<<ablocks, 256, 0, stream>>>((const uint*)xlb, (const uint*)xrb,
                                             att + 2 * HID, bias + 2 * HID, row_start, ssrc,
                                             (uint*)hbA, n);

    pool_kernel<<<dim3(N_GRAPHS, 8), 256, 0, stream>>>((const uint*)hbA, batch, n, psum);
    final_kernel<<<1, 64, 0, stream>>>(psum, batch, n, lw, lb, out);
}